// Round 9
// baseline (126.684 us; speedup 1.0000x reference)
//
#include <hip/hip_runtime.h>
#include <stdint.h>

typedef unsigned short u16;
typedef __attribute__((ext_vector_type(8))) short short8;
typedef __attribute__((ext_vector_type(4))) short short4v;
typedef __attribute__((ext_vector_type(4))) float f32x4;
typedef __attribute__((ext_vector_type(4))) unsigned short ushort4v;
typedef __attribute__((ext_vector_type(2))) unsigned int uint2v;
typedef __attribute__((ext_vector_type(4))) unsigned int uint4v;

#define NB 2
#define NS 2048
#define ND 1024
#define NH 16
#define HDIM 64
#define NHALF 32
#define QSCALE 0.18033688f   /* 0.125 * log2(e) : folds 1/sqrt(64) and exp->exp2 */
#define NEGBIG -3.0e38f      /* finite "-inf": exp2 -> 0, no NaN from arithmetic */

__device__ __forceinline__ float bf2f(u16 u) {
  union { unsigned u; float f; } v; v.u = ((unsigned)u) << 16; return v.f;
}
__device__ __forceinline__ u16 f2bf(float f) {
  union { float f; unsigned u; } v; v.f = f;
  unsigned r = v.u + 0x7fffu + ((v.u >> 16) & 1u);
  return (u16)(r >> 16);
}

// packs lo->bits[15:0], hi->bits[31:16], RNE — same rounding as f2bf
__device__ __forceinline__ unsigned cvt_pk_bf16(float lo, float hi) {
  unsigned r;
  asm("v_cvt_pk_bf16_f32 %0, %1, %2" : "=v"(r) : "v"(lo), "v"(hi));
  return r;
}

__device__ __forceinline__ void gld_lds16(const u16* g, u16* l) {
  void* gv = (void*)g;
  __builtin_amdgcn_global_load_lds((__attribute__((address_space(1))) void*)gv,
                                   (__attribute__((address_space(3))) void*)l, 16, 0, 0);
}

// ---------------- convert x (fp32 -> bf16) ----------------
__global__ void cvt_x(const float* __restrict__ x, u16* __restrict__ xb) {
  int i = blockIdx.x * 256 + threadIdx.x;
  float4 v = ((const float4*)x)[i];
  ushort4v o;
  o.x = f2bf(v.x); o.y = f2bf(v.y); o.z = f2bf(v.z); o.w = f2bf(v.w);
  ((ushort4v*)xb)[i] = o;
}

// ---------------- transpose + convert Wq/Wk/Wv (z = 0..2) ----------------
__global__ void transpose_w3(const float* __restrict__ W0, const float* __restrict__ W1,
                             const float* __restrict__ W2, u16* __restrict__ dst0) {
  __shared__ float tile[32][33];
  const int z = blockIdx.z;
  const float* W = (z == 0) ? W0 : (z == 1) ? W1 : W2;
  u16* dst = dst0 + (size_t)z * ND * ND;
  const int n0 = blockIdx.x * 32, k0 = blockIdx.y * 32;
  const int tx = threadIdx.x, ty = threadIdx.y;
#pragma unroll
  for (int i = 0; i < 4; ++i)
    tile[ty + i * 8][tx] = W[(size_t)(k0 + ty + i * 8) * ND + n0 + tx];
  __syncthreads();
#pragma unroll
  for (int i = 0; i < 4; ++i)
    dst[(size_t)(n0 + ty + i * 8) * ND + k0 + tx] = f2bf(tile[tx][ty + i * 8]);
}

__global__ void transpose_w(const float* __restrict__ W, u16* __restrict__ dst) {
  __shared__ float tile[32][33];
  const int n0 = blockIdx.x * 32, k0 = blockIdx.y * 32;
  const int tx = threadIdx.x, ty = threadIdx.y;
#pragma unroll
  for (int i = 0; i < 4; ++i)
    tile[ty + i * 8][tx] = W[(size_t)(k0 + ty + i * 8) * ND + n0 + tx];
  __syncthreads();
#pragma unroll
  for (int i = 0; i < 4; ++i)
    dst[(size_t)(n0 + ty + i * 8) * ND + k0 + tx] = f2bf(tile[tx][ty + i * 8]);
}

// ---------------- transpose V: [bh][s][d] -> VT [bh][d][s] ----------------
__global__ void transpose_v(const u16* __restrict__ Vb, u16* __restrict__ VT) {
  __shared__ u16 tile[64][72];
  const int bh = blockIdx.y, s0 = blockIdx.x << 6;
  const int tid = threadIdx.x;
  const u16* src = Vb + ((size_t)bh * NS + s0) * HDIM;
  u16* dst = VT + (size_t)bh * HDIM * NS + s0;
#pragma unroll
  for (int it = 0; it < 2; ++it) {
    int i = it * 256 + tid;
    int s = i >> 3, d0 = (i & 7) << 3;
    *(short8*)&tile[s][d0] = *(const short8*)(src + (size_t)s * HDIM + d0);
  }
  __syncthreads();
#pragma unroll
  for (int it = 0; it < 2; ++it) {
    int i = it * 256 + tid;
    int d = i >> 3, ss0 = (i & 7) << 3;
    short8 v;
#pragma unroll
    for (int e = 0; e < 8; ++e) v[e] = tile[ss0 + e][d];
    *(short8*)(dst + (size_t)d * NS + ss0) = v;
  }
}

// ---------------- QKV GEMM with fused RoPE epilogue ----------------
// C[M=4096,N=3072] = xb @ WTqkv^T. Epilogue: per-wave LDS transpose so each
// lane holds 16 consecutive d of one (s, head) row -> 8 rotate pairs -> RoPE
// (+QSCALE for Q) applied in fp32 -> 1KB-contiguous coalesced bf16 stores.
__global__ __launch_bounds__(256) void gemm_qkv(
    const u16* __restrict__ A, const u16* __restrict__ BT,
    u16* __restrict__ qo, u16* __restrict__ ko, u16* __restrict__ vo,
    const float* __restrict__ cosT, const float* __restrict__ sinT) {
  __shared__ u16 smem[8192];        // A tile [128][32] | B tile [128][32]
  __shared__ float epi[4][16][68];  // per-wave 16x64 fp32 slab (+4 pad)
  const int tid = threadIdx.x;
  const int w = tid >> 6, lane = tid & 63;
  const int lr = lane & 15, lg = lane >> 4;
  const int bm = blockIdx.y << 7, bn = blockIdx.x << 7;
  const int wr = (w >> 1) << 6, wc = (w & 1) << 6;
  f32x4 acc[4][4] = {};

  for (int kt = 0; kt < ND; kt += 32) {
#pragma unroll
    for (int r = 0; r < 2; ++r) {
      const int idx = ((r << 2) + w) * 64 + lane;
      const int row = idx >> 2, ch = (idx & 3) << 3;
      gld_lds16(A + (size_t)(bm + row) * ND + kt + ch, smem + ((r << 2) + w) * 512);
      gld_lds16(BT + (size_t)(bn + row) * ND + kt + ch, smem + 4096 + ((r << 2) + w) * 512);
    }
    __syncthreads();
    short8 af[4], bfr[4];
#pragma unroll
    for (int mi = 0; mi < 4; ++mi)
      af[mi] = *(const short8*)(smem + (wr + mi * 16 + lr) * 32 + lg * 8);
#pragma unroll
    for (int ni = 0; ni < 4; ++ni)
      bfr[ni] = *(const short8*)(smem + 4096 + (wc + ni * 16 + lr) * 32 + lg * 8);
#pragma unroll
    for (int mi = 0; mi < 4; ++mi)
#pragma unroll
      for (int ni = 0; ni < 4; ++ni)
        acc[mi][ni] = __builtin_amdgcn_mfma_f32_16x16x32_bf16(af[mi], bfr[ni], acc[mi][ni], 0, 0, 0);
    __syncthreads();
  }

  // ---- epilogue ----
  const int er = lane >> 2;                 // slab row 0..15
  const int ec = lane & 3;                  // 16-col chunk 0..3
  const int n0 = bn + wc + (ec << 4);       // block-uniform which
  const int which = n0 >> 10, hh = (n0 >> 6) & 15, d0 = n0 & 63;
  u16* dstv = which == 0 ? qo : which == 1 ? ko : vo;
  const int i0 = d0 >> 1;
  const float sc = which == 0 ? QSCALE : 1.0f;

#pragma unroll
  for (int mi = 0; mi < 4; ++mi) {
    // scatter fragments into wave-private slab (2-way banks, free)
#pragma unroll
    for (int ni = 0; ni < 4; ++ni)
#pragma unroll
      for (int j = 0; j < 4; ++j)
        epi[w][(lg << 2) + j][ni * 16 + lr] = acc[mi][ni][j];
    // gather transposed: lane -> (row er, cols ec*16..+16). Same-wave DS ops
    // are processed in order; no barrier needed for a wave-private slab.
    const int m = bm + wr + mi * 16 + er;
    const int b = m >> 11, s = m & 2047;
    float v[16];
#pragma unroll
    for (int c = 0; c < 4; ++c)
      *(f32x4*)(v + c * 4) = *(const f32x4*)(&epi[w][er][(ec << 4) + c * 4]);
    unsigned pk[8];
    if (which < 2) {
      const float4 c0 = *(const float4*)(cosT + s * NHALF + i0);
      const float4 c1 = *(const float4*)(cosT + s * NHALF + i0 + 4);
      const float4 s0 = *(const float4*)(sinT + s * NHALF + i0);
      const float4 s1 = *(const float4*)(sinT + s * NHALF + i0 + 4);
      const float cc[8] = {c0.x, c0.y, c0.z, c0.w, c1.x, c1.y, c1.z, c1.w};
      const float ss[8] = {s0.x, s0.y, s0.z, s0.w, s1.x, s1.y, s1.z, s1.w};
#pragma unroll
      for (int p = 0; p < 8; ++p) {
        const float o0 = (v[2 * p] * cc[p] - v[2 * p + 1] * ss[p]) * sc;
        const float o1 = (v[2 * p] * ss[p] + v[2 * p + 1] * cc[p]) * sc;
        pk[p] = cvt_pk_bf16(o0, o1);
      }
    } else {
#pragma unroll
      for (int p = 0; p < 8; ++p)
        pk[p] = cvt_pk_bf16(v[2 * p], v[2 * p + 1]);
    }
    u16* dp = dstv + (((size_t)(b * NH + hh) * NS + s) << 6) + d0;
    uint4v o0, o1;
    o0.x = pk[0]; o0.y = pk[1]; o0.z = pk[2]; o0.w = pk[3];
    o1.x = pk[4]; o1.y = pk[5]; o1.z = pk[6]; o1.w = pk[7];
    *(uint4v*)dp = o0;
    *(uint4v*)(dp + 8) = o1;
  }
}

// ---------------- out-proj GEMM: fo[M=4096,N=1024] = Ob @ WTo^T ----------------
// 8 waves (512 thr), wave owns 64x32; double-buffered LDS, ONE barrier per
// K-step (stage next before compute) so loads fly under the 8 MFMAs.
__global__ __launch_bounds__(512) void gemm_out(
    const u16* __restrict__ A, const u16* __restrict__ BT, float* __restrict__ fo) {
  __shared__ u16 smem[2][8192];     // per buf: A[128][32] | B[128][32]
  const int tid = threadIdx.x, w = tid >> 6, lane = tid & 63;
  const int lr = lane & 15, lg = lane >> 4;
  const int bm = blockIdx.y << 7, bn = blockIdx.x << 7;
  const int wr = (w >> 2) << 6, wc = (w & 3) << 5;
  f32x4 acc[4][2] = {};
  const u16* ag = A + (size_t)(bm + w * 16 + (lane >> 2)) * ND + ((lane & 3) << 3);
  const u16* bg = BT + (size_t)(bn + w * 16 + (lane >> 2)) * ND + ((lane & 3) << 3);

#define GSTAGE(BUF, KT)                                  \
  {                                                      \
    gld_lds16(ag + (KT), &smem[BUF][w * 512]);           \
    gld_lds16(bg + (KT), &smem[BUF][4096 + w * 512]);    \
  }

  GSTAGE(0, 0);
  __syncthreads();
  int cur = 0;
  for (int kt = 0; kt < ND; kt += 32) {
    if (kt + 32 < ND) GSTAGE(cur ^ 1, kt + 32);
    const u16* As = smem[cur];
    const u16* Bs = smem[cur] + 4096;
    short8 af[4], bf[2];
#pragma unroll
    for (int mi = 0; mi < 4; ++mi)
      af[mi] = *(const short8*)(As + (wr + mi * 16 + lr) * 32 + lg * 8);
#pragma unroll
    for (int ni = 0; ni < 2; ++ni)
      bf[ni] = *(const short8*)(Bs + (wc + ni * 16 + lr) * 32 + lg * 8);
    __builtin_amdgcn_s_setprio(1);
#pragma unroll
    for (int mi = 0; mi < 4; ++mi)
#pragma unroll
      for (int ni = 0; ni < 2; ++ni)
        acc[mi][ni] = __builtin_amdgcn_mfma_f32_16x16x32_bf16(af[mi], bf[ni], acc[mi][ni], 0, 0, 0);
    __builtin_amdgcn_s_setprio(0);
    __syncthreads();                 // drains vmcnt(0): next buf ready, WAR safe
    cur ^= 1;
  }

#pragma unroll
  for (int mi = 0; mi < 4; ++mi)
#pragma unroll
    for (int ni = 0; ni < 2; ++ni)
#pragma unroll
      for (int j = 0; j < 4; ++j) {
        const int m = bm + wr + mi * 16 + (lg << 2) + j;
        const int n = bn + wc + ni * 16 + lr;
        fo[(size_t)m * ND + n] = acc[mi][ni][j];
      }
}

// ---------------- flash attention (causal), paired q-tiles ----------------
__global__ __launch_bounds__(256, 4) void attn_k(
    const u16* __restrict__ Qb, const u16* __restrict__ Kb,
    const u16* __restrict__ VT, u16* __restrict__ Ob) {
  __shared__ u16 K2[2][4096];   // [kv][d], rows 128B, XOR-swizzled
  __shared__ u16 V2[2][4096];   // [d][kv], rows 128B, XOR-swizzled
  __shared__ u16 Pl[4][1024];   // per wave [q=16][kv=64], rows 128B, XOR-swizzled
  const int tid = threadIdx.x, w = tid >> 6, lane = tid & 63;
  const int lr = lane & 15, lg = lane >> 4;
  const int bid = blockIdx.x;
  const int xcd = bid & 7, i = bid >> 3;          // i in 0..63
  const int bh = xcd * 4 + (i & 3);
  const int pair = i >> 2;                        // 0..15
  const int b = bh >> 4, h = bh & 15;
  const u16* Qp = Qb + (size_t)bh * NS * HDIM;
  const u16* Kp = Kb + (size_t)bh * NS * HDIM;
  const u16* Vp = VT + (size_t)bh * NS * HDIM;    // [d][s]

  int kf_off[4][2], vb_off[4][2], pw_off[4], pa_off[2];
#pragma unroll
  for (int u = 0; u < 4; ++u) {
    const int kvr = (u << 4) + lr;
#pragma unroll
    for (int c = 0; c < 2; ++c)
      kf_off[u][c] = kvr * 64 + ((((c << 6) + (lg << 4)) ^ ((kvr & 7) << 4)) >> 1);
  }
#pragma unroll
  for (int dn = 0; dn < 4; ++dn) {
    const int d = (dn << 4) + lr;
#pragma unroll
    for (int ks = 0; ks < 2; ++ks)
      vb_off[dn][ks] = d * 64 + ((((ks << 6) + (lg << 4)) ^ ((d & 7) << 4)) >> 1);
  }
#pragma unroll
  for (int u = 0; u < 4; ++u)
    pw_off[u] = lr * 64 + ((((u << 5) + (lg << 3)) ^ ((lr & 7) << 4)) >> 1);
#pragma unroll
  for (int ks = 0; ks < 2; ++ks)
    pa_off[ks] = lr * 64 + ((((ks << 6) + (lg << 4)) ^ ((lr & 7) << 4)) >> 1);
  u16* Pw = &Pl[w][0];

  const int rr = tid >> 3, slot = tid & 7;
  const int soff = (((slot << 4) ^ ((rr & 7) << 4)) >> 1);
  const u16* kg0 = Kp + rr * HDIM + soff;
  const u16* kg1 = Kp + (rr + 32) * HDIM + soff;
  const u16* vg0 = Vp + (size_t)rr * NS + soff;
  const u16* vg1 = Vp + (size_t)(rr + 32) * NS + soff;

#define STAGE(BUFI, KV0)                                         \
  {                                                              \
    gld_lds16(kg0 + (KV0) * HDIM, &K2[BUFI][w * 512]);           \
    gld_lds16(kg1 + (KV0) * HDIM, &K2[BUFI][(4 + w) * 512]);     \
    gld_lds16(vg0 + (KV0),        &V2[BUFI][w * 512]);           \
    gld_lds16(vg1 + (KV0),        &V2[BUFI][(4 + w) * 512]);     \
  }

#define STEP(BUF, KVT)                                                            \
  {                                                                               \
    const int kv0 = (KVT) << 6;                                                   \
    if ((KVT) + 1 < nst) STAGE(BUF ^ 1, kv0 + 64);                                \
    const u16* Kl = K2[BUF];                                                      \
    const u16* Vl = V2[BUF];                                                      \
    f32x4 st[4] = {};                                                             \
    __builtin_amdgcn_s_setprio(1);                                                \
    _Pragma("unroll") for (int u = 0; u < 4; ++u)                                 \
      _Pragma("unroll") for (int c = 0; c < 2; ++c)                               \
        st[u] = __builtin_amdgcn_mfma_f32_16x16x32_bf16(                          \
            *(const short8*)(Kl + kf_off[u][c]), qf[c], st[u], 0, 0, 0);          \
    __builtin_amdgcn_s_setprio(0);                                                \
    if (kv0 + 63 > qw) {                                                          \
      _Pragma("unroll") for (int u = 0; u < 4; ++u)                               \
        _Pragma("unroll") for (int j = 0; j < 4; ++j) {                           \
          const int kvg = kv0 + (u << 4) + (lg << 2) + j;                         \
          if (kvg > q_col) st[u][j] = NEGBIG;                                     \
        }                                                                         \
    }                                                                             \
    _Pragma("unroll") for (int u = 0; u < 4; ++u) {                               \
      const float e0 = __builtin_amdgcn_exp2f(st[u][0]);                          \
      const float e1 = __builtin_amdgcn_exp2f(st[u][1]);                          \
      const float e2 = __builtin_amdgcn_exp2f(st[u][2]);                          \
      const float e3 = __builtin_amdgcn_exp2f(st[u][3]);                          \
      lacc += (e0 + e1) + (e2 + e3);                                              \
      uint2v pk;                                                                  \
      pk.x = cvt_pk_bf16(e0, e1);                                                 \
      pk.y = cvt_pk_bf16(e2, e3);                                                 \
      *(uint2v*)(Pw + pw_off[u]) = pk;                                            \
    }                                                                             \
    {                                                                             \
      short8 pa0 = *(const short8*)(Pw + pa_off[0]);                              \
      short8 pa1 = *(const short8*)(Pw + pa_off[1]);                              \
      __builtin_amdgcn_s_setprio(1);                                              \
      _Pragma("unroll") for (int dn = 0; dn < 4; ++dn) {                          \
        o[dn] = __builtin_amdgcn_mfma_f32_16x16x32_bf16(                          \
            pa0, *(const short8*)(Vl + vb_off[dn][0]), o[dn], 0, 0, 0);           \
        o[dn] = __builtin_amdgcn_mfma_f32_16x16x32_bf16(                          \
            pa1, *(const short8*)(Vl + vb_off[dn][1]), o[dn], 0, 0, 0);           \
      }                                                                           \
      __builtin_amdgcn_s_setprio(0);                                              \
    }                                                                             \
    __syncthreads();                                                              \
  }

  for (int seg = 0; seg < 2; ++seg) {
    const int tile = seg ? pair : 31 - pair;      // long tile first, short second
    const int q0 = tile << 6;
    const int qw = q0 + w * 16;
    const int q_col = qw + lr;
    const int nst = tile + 1;

    short8 qf[2];
#pragma unroll
    for (int c = 0; c < 2; ++c)
      qf[c] = *(const short8*)(Qp + (size_t)(qw + lr) * HDIM + c * 32 + lg * 8);

    f32x4 o[4] = {};
    float lacc = 0.f;

    STAGE(0, 0);
    __syncthreads();

    int kvt = 0;
    for (; kvt + 2 <= nst; kvt += 2) {
      STEP(0, kvt);
      STEP(1, kvt + 1);
    }
    if (kvt < nst) STEP(0, kvt);

    float rs = lacc;
    rs += __shfl_xor(rs, 16);
    rs += __shfl_xor(rs, 32);
    float li[4];
#pragma unroll
    for (int j = 0; j < 4; ++j) li[j] = 1.0f / __shfl(rs, (lg << 2) + j);
#pragma unroll
    for (int dn = 0; dn < 4; ++dn)
#pragma unroll
      for (int j = 0; j < 4; ++j) {
        const int m = b * NS + qw + (lg << 2) + j;
        const int col = h * 64 + dn * 16 + lr;
        Ob[(size_t)m * ND + col] = f2bf(o[dn][j] * li[j]);
      }
  }
}

extern "C" void kernel_launch(void* const* d_in, const int* in_sizes, int n_in,
                              void* d_out, int out_size, void* d_ws, size_t ws_size,
                              hipStream_t stream) {
  const float* x  = (const float*)d_in[0];
  const float* fc = (const float*)d_in[1];
  const float* fs = (const float*)d_in[2];
  const float* Wq = (const float*)d_in[3];
  const float* Wk = (const float*)d_in[4];
  const float* Wv = (const float*)d_in[5];
  const float* Wo = (const float*)d_in[6];
  float* out = (float*)d_out;
  char* ws = (char*)d_ws;

  // Workspace timeline (40 MB):
  //  0- 8MB: xb -> Ob   8-16MB: WTqkv -> VT   16-24MB: Qb   24-32MB: Kb
  // 32-40MB: Vb -> WTo
  u16* xb    = (u16*)(ws);
  u16* WTqkv = (u16*)(ws + (size_t)(8u << 20));
  u16* VT    = (u16*)(ws + (size_t)(8u << 20));
  u16* Qb    = (u16*)(ws + (size_t)(16u << 20));
  u16* Kb    = (u16*)(ws + (size_t)(24u << 20));
  u16* Vb    = (u16*)(ws + (size_t)(32u << 20));
  u16* WTo   = (u16*)(ws + (size_t)(32u << 20));
  u16* Ob    = xb;

  cvt_x<<<4096, 256, 0, stream>>>(x, xb);
  transpose_w3<<<dim3(32, 32, 3), dim3(32, 8), 0, stream>>>(Wq, Wk, Wv, WTqkv);
  gemm_qkv<<<dim3(24, 32), 256, 0, stream>>>(xb, WTqkv, Qb, Kb, Vb, fc, fs);
  transpose_v<<<dim3(32, 32), 256, 0, stream>>>(Vb, VT);
  transpose_w<<<dim3(32, 32), dim3(32, 8), 0, stream>>>(Wo, WTo);
  attn_k<<<512, 256, 0, stream>>>(Qb, Kb, VT, Ob);
  gemm_out<<<dim3(8, 32), 512, 0, stream>>>(Ob, WTo, out);
}

// Round 10
// 107.732 us; speedup vs baseline: 1.1759x; 1.1759x over previous
//
#include <hip/hip_runtime.h>
#include <stdint.h>

typedef unsigned short u16;
typedef __attribute__((ext_vector_type(8))) short short8;
typedef __attribute__((ext_vector_type(4))) short short4v;
typedef __attribute__((ext_vector_type(4))) float f32x4;
typedef __attribute__((ext_vector_type(4))) unsigned short ushort4v;
typedef __attribute__((ext_vector_type(2))) unsigned int uint2v;

#define NB 2
#define NS 2048
#define ND 1024
#define NH 16
#define HDIM 64
#define NHALF 32
#define QSCALE 0.18033688f   /* 0.125 * log2(e) : folds 1/sqrt(64) and exp->exp2 */
#define NEGBIG -3.0e38f      /* finite "-inf": exp2 -> 0, no NaN from arithmetic */

__device__ __forceinline__ float bf2f(u16 u) {
  union { unsigned u; float f; } v; v.u = ((unsigned)u) << 16; return v.f;
}
__device__ __forceinline__ u16 f2bf(float f) {
  union { float f; unsigned u; } v; v.f = f;
  unsigned r = v.u + 0x7fffu + ((v.u >> 16) & 1u);
  return (u16)(r >> 16);
}

// packs lo->bits[15:0], hi->bits[31:16], RNE — same rounding as f2bf
__device__ __forceinline__ unsigned cvt_pk_bf16(float lo, float hi) {
  unsigned r;
  asm("v_cvt_pk_bf16_f32 %0, %1, %2" : "=v"(r) : "v"(lo), "v"(hi));
  return r;
}

__device__ __forceinline__ void gld_lds16(const u16* g, u16* l) {
  void* gv = (void*)g;
  __builtin_amdgcn_global_load_lds((__attribute__((address_space(1))) void*)gv,
                                   (__attribute__((address_space(3))) void*)l, 16, 0, 0);
}

// ---------------- convert x (fp32 -> bf16) ----------------
__global__ void cvt_x(const float* __restrict__ x, u16* __restrict__ xb) {
  int i = blockIdx.x * 256 + threadIdx.x;
  float4 v = ((const float4*)x)[i];
  ushort4v o;
  o.x = f2bf(v.x); o.y = f2bf(v.y); o.z = f2bf(v.z); o.w = f2bf(v.w);
  ((ushort4v*)xb)[i] = o;
}

// ---------------- transpose + convert Wq/Wk/Wv (z = 0..2) ----------------
__global__ void transpose_w3(const float* __restrict__ W0, const float* __restrict__ W1,
                             const float* __restrict__ W2, u16* __restrict__ dst0) {
  __shared__ float tile[32][33];
  const int z = blockIdx.z;
  const float* W = (z == 0) ? W0 : (z == 1) ? W1 : W2;
  u16* dst = dst0 + (size_t)z * ND * ND;
  const int n0 = blockIdx.x * 32, k0 = blockIdx.y * 32;
  const int tx = threadIdx.x, ty = threadIdx.y;
#pragma unroll
  for (int i = 0; i < 4; ++i)
    tile[ty + i * 8][tx] = W[(size_t)(k0 + ty + i * 8) * ND + n0 + tx];
  __syncthreads();
#pragma unroll
  for (int i = 0; i < 4; ++i)
    dst[(size_t)(n0 + ty + i * 8) * ND + k0 + tx] = f2bf(tile[tx][ty + i * 8]);
}

__global__ void transpose_w(const float* __restrict__ W, u16* __restrict__ dst) {
  __shared__ float tile[32][33];
  const int n0 = blockIdx.x * 32, k0 = blockIdx.y * 32;
  const int tx = threadIdx.x, ty = threadIdx.y;
#pragma unroll
  for (int i = 0; i < 4; ++i)
    tile[ty + i * 8][tx] = W[(size_t)(k0 + ty + i * 8) * ND + n0 + tx];
  __syncthreads();
#pragma unroll
  for (int i = 0; i < 4; ++i)
    dst[(size_t)(n0 + ty + i * 8) * ND + k0 + tx] = f2bf(tile[tx][ty + i * 8]);
}

// ---------------- transpose V: [bh][s][d] -> VT [bh][d][s] ----------------
__global__ void transpose_v(const u16* __restrict__ Vb, u16* __restrict__ VT) {
  __shared__ u16 tile[64][72];
  const int bh = blockIdx.y, s0 = blockIdx.x << 6;
  const int tid = threadIdx.x;
  const u16* src = Vb + ((size_t)bh * NS + s0) * HDIM;
  u16* dst = VT + (size_t)bh * HDIM * NS + s0;
#pragma unroll
  for (int it = 0; it < 2; ++it) {
    int i = it * 256 + tid;
    int s = i >> 3, d0 = (i & 7) << 3;
    *(short8*)&tile[s][d0] = *(const short8*)(src + (size_t)s * HDIM + d0);
  }
  __syncthreads();
#pragma unroll
  for (int it = 0; it < 2; ++it) {
    int i = it * 256 + tid;
    int d = i >> 3, ss0 = (i & 7) << 3;
    short8 v;
#pragma unroll
    for (int e = 0; e < 8; ++e) v[e] = tile[ss0 + e][d];
    *(short8*)(dst + (size_t)d * NS + ss0) = v;
  }
}

// ---------------- unified GEMM, BK=64, XOR-swizzled LDS ----------------
// C[M, N] = A[M,1024] @ BT[N,1024]^T. Tile: (MI*32) x 128, 4 waves.
// LDS rows are 128B (8 x 16B slots); slot' = slot ^ (row&7) kills the 8-way
// ds_read_b128 bank conflict of the old 64B-row layout (T2; swizzle baked
// into the per-lane GLOBAL source, LDS dest linear — rule #21).
// MODE 0: scatter bf16 into Q/K/V [b][h][s][d] (proven R8 epilogue).
// MODE 1: fp32 rows into fo.
template<int MI, int MODE>
__global__ __launch_bounds__(256) void gemm64(
    const u16* __restrict__ A, const u16* __restrict__ BT,
    u16* __restrict__ qo, u16* __restrict__ ko, u16* __restrict__ vo,
    float* __restrict__ fo) {
  __shared__ u16 smem[MI * 2048 + 8192];   // A[(MI*32)][64] | B[128][64]
  const int tid = threadIdx.x;
  const int w = tid >> 6, lane = tid & 63;
  const int lr = lane & 15, lg = lane >> 4;
  const int bm = blockIdx.y * (MI * 32), bn = blockIdx.x << 7;
  const int wr = (w >> 1) * (MI * 16), wc = (w & 1) << 6;
  f32x4 acc[MI][4] = {};

  // per-thread staging sources with inverse swizzle on the global column
  const int arow = tid >> 3;                       // 0..31
  const int aslot = (tid & 7) ^ (arow & 7);
  const u16* ags = A + (size_t)(bm + arow) * ND + (aslot << 3);
  const u16* bgs = BT + (size_t)(bn + arow) * ND + (aslot << 3);
  u16* const As = smem;
  u16* const Bs = smem + MI * 2048;

  // hoisted swizzled ds_read offsets (u16 units)
  int af_off[MI][2], bf_off[4][2];
#pragma unroll
  for (int mi = 0; mi < MI; ++mi)
#pragma unroll
    for (int kk = 0; kk < 2; ++kk)
      af_off[mi][kk] = (wr + mi * 16 + lr) * 64 + ((((kk << 2) + lg) ^ (lr & 7)) << 3);
#pragma unroll
  for (int ni = 0; ni < 4; ++ni)
#pragma unroll
    for (int kk = 0; kk < 2; ++kk)
      bf_off[ni][kk] = (wc + ni * 16 + lr) * 64 + ((((kk << 2) + lg) ^ (lr & 7)) << 3);

  for (int kt = 0; kt < ND; kt += 64) {
#pragma unroll
    for (int it = 0; it < MI; ++it)
      gld_lds16(ags + it * (32 * ND) + kt, As + it * 2048 + w * 512);
#pragma unroll
    for (int it = 0; it < 4; ++it)
      gld_lds16(bgs + it * (32 * ND) + kt, Bs + it * 2048 + w * 512);
    __syncthreads();
#pragma unroll
    for (int kk = 0; kk < 2; ++kk) {
      short8 af[MI], bfr[4];
#pragma unroll
      for (int mi = 0; mi < MI; ++mi)
        af[mi] = *(const short8*)(As + af_off[mi][kk]);
#pragma unroll
      for (int ni = 0; ni < 4; ++ni)
        bfr[ni] = *(const short8*)(Bs + bf_off[ni][kk]);
#pragma unroll
      for (int mi = 0; mi < MI; ++mi)
#pragma unroll
        for (int ni = 0; ni < 4; ++ni)
          acc[mi][ni] = __builtin_amdgcn_mfma_f32_16x16x32_bf16(af[mi], bfr[ni], acc[mi][ni], 0, 0, 0);
    }
    __syncthreads();
  }

  if (MODE == 0) {
#pragma unroll
    for (int mi = 0; mi < MI; ++mi) {
#pragma unroll
      for (int ni = 0; ni < 4; ++ni) {
        const int n = bn + wc + ni * 16 + lr;
        const int which = n >> 10, hh = (n >> 6) & 15, d = n & 63;
        u16* dst = which == 0 ? qo : which == 1 ? ko : vo;
#pragma unroll
        for (int j = 0; j < 4; ++j) {
          const int m = bm + wr + mi * 16 + (lg << 2) + j;
          const int b = m >> 11, s = m & 2047;
          dst[(((size_t)(b * NH + hh) * NS + s) << 6) + d] = f2bf(acc[mi][ni][j]);
        }
      }
    }
  } else {
#pragma unroll
    for (int mi = 0; mi < MI; ++mi)
#pragma unroll
      for (int ni = 0; ni < 4; ++ni)
#pragma unroll
        for (int j = 0; j < 4; ++j) {
          const int m = bm + wr + mi * 16 + (lg << 2) + j;
          const int n = bn + wc + ni * 16 + lr;
          fo[(size_t)m * ND + n] = acc[mi][ni][j];
        }
  }
}

// ---------------- RoPE on Q,K in place (vectorized); Q pre-scaled ----------------
__global__ void rope_k(u16* __restrict__ Qb, u16* __restrict__ Kb,
                       const float* __restrict__ cosT, const float* __restrict__ sinT) {
  int t = blockIdx.x * 256 + threadIdx.x;   // B*H*S*8 threads, 8 bf16 each
  int g = t & 7;
  int s = (t >> 3) & 2047;
  int bh = t >> 14;
  float4 c4 = *(const float4*)(cosT + s * NHALF + (g << 2));
  float4 s4 = *(const float4*)(sinT + s * NHALF + (g << 2));
  size_t off = (((size_t)bh * NS + s) << 6) + (g << 3);
  short8 q = *(const short8*)(Qb + off);
  short8 k = *(const short8*)(Kb + off);
  float cc[4] = {c4.x, c4.y, c4.z, c4.w}, ss[4] = {s4.x, s4.y, s4.z, s4.w};
  short8 qo, ko;
#pragma unroll
  for (int p = 0; p < 4; ++p) {
    float q0 = bf2f((u16)q[2 * p]), q1 = bf2f((u16)q[2 * p + 1]);
    qo[2 * p]     = (short)f2bf((q0 * cc[p] - q1 * ss[p]) * QSCALE);
    qo[2 * p + 1] = (short)f2bf((q0 * ss[p] + q1 * cc[p]) * QSCALE);
    float k0 = bf2f((u16)k[2 * p]), k1 = bf2f((u16)k[2 * p + 1]);
    ko[2 * p]     = (short)f2bf(k0 * cc[p] - k1 * ss[p]);
    ko[2 * p + 1] = (short)f2bf(k0 * ss[p] + k1 * cc[p]);
  }
  *(short8*)(Qb + off) = qo;
  *(short8*)(Kb + off) = ko;
}

// ---------------- flash attention (causal), paired q-tiles ----------------
__global__ __launch_bounds__(256, 4) void attn_k(
    const u16* __restrict__ Qb, const u16* __restrict__ Kb,
    const u16* __restrict__ VT, u16* __restrict__ Ob) {
  __shared__ u16 K2[2][4096];   // [kv][d], rows 128B, XOR-swizzled
  __shared__ u16 V2[2][4096];   // [d][kv], rows 128B, XOR-swizzled
  __shared__ u16 Pl[4][1024];   // per wave [q=16][kv=64], rows 128B, XOR-swizzled
  const int tid = threadIdx.x, w = tid >> 6, lane = tid & 63;
  const int lr = lane & 15, lg = lane >> 4;
  const int bid = blockIdx.x;
  const int xcd = bid & 7, i = bid >> 3;          // i in 0..63
  const int bh = xcd * 4 + (i & 3);
  const int pair = i >> 2;                        // 0..15
  const int b = bh >> 4, h = bh & 15;
  const u16* Qp = Qb + (size_t)bh * NS * HDIM;
  const u16* Kp = Kb + (size_t)bh * NS * HDIM;
  const u16* Vp = VT + (size_t)bh * NS * HDIM;    // [d][s]

  int kf_off[4][2], vb_off[4][2], pw_off[4], pa_off[2];
#pragma unroll
  for (int u = 0; u < 4; ++u) {
    const int kvr = (u << 4) + lr;
#pragma unroll
    for (int c = 0; c < 2; ++c)
      kf_off[u][c] = kvr * 64 + ((((c << 6) + (lg << 4)) ^ ((kvr & 7) << 4)) >> 1);
  }
#pragma unroll
  for (int dn = 0; dn < 4; ++dn) {
    const int d = (dn << 4) + lr;
#pragma unroll
    for (int ks = 0; ks < 2; ++ks)
      vb_off[dn][ks] = d * 64 + ((((ks << 6) + (lg << 4)) ^ ((d & 7) << 4)) >> 1);
  }
#pragma unroll
  for (int u = 0; u < 4; ++u)
    pw_off[u] = lr * 64 + ((((u << 5) + (lg << 3)) ^ ((lr & 7) << 4)) >> 1);
#pragma unroll
  for (int ks = 0; ks < 2; ++ks)
    pa_off[ks] = lr * 64 + ((((ks << 6) + (lg << 4)) ^ ((lr & 7) << 4)) >> 1);
  u16* Pw = &Pl[w][0];

  const int rr = tid >> 3, slot = tid & 7;
  const int soff = (((slot << 4) ^ ((rr & 7) << 4)) >> 1);
  const u16* kg0 = Kp + rr * HDIM + soff;
  const u16* kg1 = Kp + (rr + 32) * HDIM + soff;
  const u16* vg0 = Vp + (size_t)rr * NS + soff;
  const u16* vg1 = Vp + (size_t)(rr + 32) * NS + soff;

#define STAGE(BUFI, KV0)                                         \
  {                                                              \
    gld_lds16(kg0 + (KV0) * HDIM, &K2[BUFI][w * 512]);           \
    gld_lds16(kg1 + (KV0) * HDIM, &K2[BUFI][(4 + w) * 512]);     \
    gld_lds16(vg0 + (KV0),        &V2[BUFI][w * 512]);           \
    gld_lds16(vg1 + (KV0),        &V2[BUFI][(4 + w) * 512]);     \
  }

#define STEP(BUF, KVT)                                                            \
  {                                                                               \
    const int kv0 = (KVT) << 6;                                                   \
    if ((KVT) + 1 < nst) STAGE(BUF ^ 1, kv0 + 64);                                \
    const u16* Kl = K2[BUF];                                                      \
    const u16* Vl = V2[BUF];                                                      \
    f32x4 st[4] = {};                                                             \
    __builtin_amdgcn_s_setprio(1);                                                \
    _Pragma("unroll") for (int u = 0; u < 4; ++u)                                 \
      _Pragma("unroll") for (int c = 0; c < 2; ++c)                               \
        st[u] = __builtin_amdgcn_mfma_f32_16x16x32_bf16(                          \
            *(const short8*)(Kl + kf_off[u][c]), qf[c], st[u], 0, 0, 0);          \
    __builtin_amdgcn_s_setprio(0);                                                \
    if (kv0 + 63 > qw) {                                                          \
      _Pragma("unroll") for (int u = 0; u < 4; ++u)                               \
        _Pragma("unroll") for (int j = 0; j < 4; ++j) {                           \
          const int kvg = kv0 + (u << 4) + (lg << 2) + j;                         \
          if (kvg > q_col) st[u][j] = NEGBIG;                                     \
        }                                                                         \
    }                                                                             \
    _Pragma("unroll") for (int u = 0; u < 4; ++u) {                               \
      const float e0 = __builtin_amdgcn_exp2f(st[u][0]);                          \
      const float e1 = __builtin_amdgcn_exp2f(st[u][1]);                          \
      const float e2 = __builtin_amdgcn_exp2f(st[u][2]);                          \
      const float e3 = __builtin_amdgcn_exp2f(st[u][3]);                          \
      lacc += (e0 + e1) + (e2 + e3);                                              \
      uint2v pk;                                                                  \
      pk.x = cvt_pk_bf16(e0, e1);                                                 \
      pk.y = cvt_pk_bf16(e2, e3);                                                 \
      *(uint2v*)(Pw + pw_off[u]) = pk;                                            \
    }                                                                             \
    {                                                                             \
      short8 pa0 = *(const short8*)(Pw + pa_off[0]);                              \
      short8 pa1 = *(const short8*)(Pw + pa_off[1]);                              \
      __builtin_amdgcn_s_setprio(1);                                              \
      _Pragma("unroll") for (int dn = 0; dn < 4; ++dn) {                          \
        o[dn] = __builtin_amdgcn_mfma_f32_16x16x32_bf16(                          \
            pa0, *(const short8*)(Vl + vb_off[dn][0]), o[dn], 0, 0, 0);           \
        o[dn] = __builtin_amdgcn_mfma_f32_16x16x32_bf16(                          \
            pa1, *(const short8*)(Vl + vb_off[dn][1]), o[dn], 0, 0, 0);           \
      }                                                                           \
      __builtin_amdgcn_s_setprio(0);                                              \
    }                                                                             \
    __syncthreads();                                                              \
  }

  for (int seg = 0; seg < 2; ++seg) {
    const int tile = seg ? pair : 31 - pair;      // long tile first, short second
    const int q0 = tile << 6;
    const int qw = q0 + w * 16;
    const int q_col = qw + lr;
    const int nst = tile + 1;

    short8 qf[2];
#pragma unroll
    for (int c = 0; c < 2; ++c)
      qf[c] = *(const short8*)(Qp + (size_t)(qw + lr) * HDIM + c * 32 + lg * 8);

    f32x4 o[4] = {};
    float lacc = 0.f;

    STAGE(0, 0);
    __syncthreads();

    int kvt = 0;
    for (; kvt + 2 <= nst; kvt += 2) {
      STEP(0, kvt);
      STEP(1, kvt + 1);
    }
    if (kvt < nst) STEP(0, kvt);

    float rs = lacc;
    rs += __shfl_xor(rs, 16);
    rs += __shfl_xor(rs, 32);
    float li[4];
#pragma unroll
    for (int j = 0; j < 4; ++j) li[j] = 1.0f / __shfl(rs, (lg << 2) + j);
#pragma unroll
    for (int dn = 0; dn < 4; ++dn)
#pragma unroll
      for (int j = 0; j < 4; ++j) {
        const int m = b * NS + qw + (lg << 2) + j;
        const int col = h * 64 + dn * 16 + lr;
        Ob[(size_t)m * ND + col] = f2bf(o[dn][j] * li[j]);
      }
  }
}

extern "C" void kernel_launch(void* const* d_in, const int* in_sizes, int n_in,
                              void* d_out, int out_size, void* d_ws, size_t ws_size,
                              hipStream_t stream) {
  const float* x  = (const float*)d_in[0];
  const float* fc = (const float*)d_in[1];
  const float* fs = (const float*)d_in[2];
  const float* Wq = (const float*)d_in[3];
  const float* Wk = (const float*)d_in[4];
  const float* Wv = (const float*)d_in[5];
  const float* Wo = (const float*)d_in[6];
  float* out = (float*)d_out;
  char* ws = (char*)d_ws;

  // Workspace timeline (40 MB):
  //  0- 8MB: xb -> Ob   8-16MB: WTqkv -> VT   16-24MB: Qb   24-32MB: Kb
  // 32-40MB: Vb -> WTo
  u16* xb    = (u16*)(ws);
  u16* WTqkv = (u16*)(ws + (size_t)(8u << 20));
  u16* VT    = (u16*)(ws + (size_t)(8u << 20));
  u16* Qb    = (u16*)(ws + (size_t)(16u << 20));
  u16* Kb    = (u16*)(ws + (size_t)(24u << 20));
  u16* Vb    = (u16*)(ws + (size_t)(32u << 20));
  u16* WTo   = (u16*)(ws + (size_t)(32u << 20));
  u16* Ob    = xb;

  cvt_x<<<4096, 256, 0, stream>>>(x, xb);
  transpose_w3<<<dim3(32, 32, 3), dim3(32, 8), 0, stream>>>(Wq, Wk, Wv, WTqkv);
  gemm64<4, 0><<<dim3(24, 32), 256, 0, stream>>>(xb, WTqkv, Qb, Kb, Vb, nullptr);
  rope_k<<<2048, 256, 0, stream>>>(Qb, Kb, fc, fs);
  transpose_v<<<dim3(32, 32), 256, 0, stream>>>(Vb, VT);
  transpose_w<<<dim3(32, 32), dim3(32, 8), 0, stream>>>(Wo, WTo);
  attn_k<<<512, 256, 0, stream>>>(Qb, Kb, VT, Ob);
  gemm64<2, 1><<<dim3(8, 64), 256, 0, stream>>>(Ob, WTo, nullptr, nullptr, nullptr, out);
}